// Round 2
// baseline (276.053 us; speedup 1.0000x reference)
//
#include <hip/hip_runtime.h>
#include <stdint.h>

// Problem constants (LieAction): B=16384, K=64, M=6, NUM_ACTIONS=16
#define BATCH 16384
#define KSUB 64
#define MDIM 6
#define MM 36            // floats per (b,k) block
#define NACT 16
#define F4PB 9           // float4 per block
#define WGT 64           // threads per wg == blocks per wg (single wave)

typedef float f32x4 __attribute__((ext_vector_type(4)));

// Kernel 1: R[a][k] = expm( act_params[a,k] * (L_k - L_k^T) ), fp32 Taylor n<=10.
// ||A||_inf <~ 0.05 -> truncation error ~1e-12. ~4 us, negligible.
__global__ void expm_table_kernel(const float* __restrict__ act_params, // [NACT,KSUB]
                                  const float* __restrict__ basis,      // [KSUB,36]
                                  float* __restrict__ Rtab)             // [NACT*KSUB,36]
{
    int gid = blockIdx.x * blockDim.x + threadIdx.x;
    if (gid >= NACT * KSUB) return;
    int a = gid / KSUB;
    int k = gid - a * KSUB;

    float L[MM];
#pragma unroll
    for (int i = 0; i < MM; ++i) L[i] = basis[k * MM + i];
    float p = act_params[a * KSUB + k];

    float A[MM];
#pragma unroll
    for (int i = 0; i < MDIM; ++i)
#pragma unroll
        for (int j = 0; j < MDIM; ++j)
            A[i * MDIM + j] = p * (L[i * MDIM + j] - L[j * MDIM + i]);

    float E[MM], T[MM];
#pragma unroll
    for (int i = 0; i < MM; ++i) { E[i] = 0.f; T[i] = 0.f; }
#pragma unroll
    for (int i = 0; i < MDIM; ++i) { E[i * MDIM + i] = 1.f; T[i * MDIM + i] = 1.f; }

    for (int n = 1; n <= 10; ++n) {
        float Tn[MM];
        float inv = 1.0f / (float)n;
#pragma unroll
        for (int i = 0; i < MDIM; ++i)
#pragma unroll
            for (int l = 0; l < MDIM; ++l) {
                float s = 0.f;
#pragma unroll
                for (int j = 0; j < MDIM; ++j)
                    s += A[i * MDIM + j] * T[j * MDIM + l];
                Tn[i * MDIM + l] = s * inv;
            }
#pragma unroll
        for (int i = 0; i < MM; ++i) { T[i] = Tn[i]; E[i] += Tn[i]; }
    }
#pragma unroll
    for (int i = 0; i < MM; ++i) Rtab[gid * MM + i] = E[i];
}

// Kernel 2: out[b,k] = R[act[b],k] @ G[b,k]  (6x6 @ 6x6, fp32)
// One 64-thread (single-wave) wg per batch row b: thread k owns block (b,k).
//
// LDS: LINEAR pitch-36 floats (144 B/row, no pad) -> global_load_lds direct
// staging works (needs linear dest). Bank analysis at stride 144 B:
//   ds_*_b128 at 144t+16q: dword-bank 4(t+q) mod 32 -> the 8 lane-groups'
//   4-bank spans tile all 32 banks at exactly 8 dwords/bank == the 8-cycle
//   data minimum for 1 KB -> effectively conflict-free.
//   ds_*_b64 would hit only even banks (2x penalty) -> NONE used anywhere.
// All LDS traffic is b128: 9 DMA writes + 9 G reads + 9 O writes + 9 gather
// reads per wave (vs 144 b32 ops in the padded-pitch version).
//
// MAC is restructured per-G-float4 so G never lives as a 36-reg array:
// for each G element (j,l): O[:,l] += R[:,j] * g. Live set: R(36)+O(36)+g(4)
// + addressing ~= 90 VGPR -> fits the 128 cap from __launch_bounds__(64,4),
// no spill. LDS 9216 B -> 16 wg/CU (4 waves/SIMD).
__global__ __launch_bounds__(WGT, 4) void apply_kernel(
    const f32x4* __restrict__ gf4,           // B*K*9 float4
    const int* __restrict__ act,             // [B] int32
    const float* __restrict__ Rtab,          // [NACT*KSUB*36] f32
    f32x4* __restrict__ out4)                // B*K*9 float4
{
    __shared__ f32x4 lds4[WGT * F4PB];       // 9216 B, linear
    const int tid = threadIdx.x;
    const int b = blockIdx.x;
    const size_t base4 = (size_t)b * (WGT * F4PB);

    // 1) async global->LDS stage: issue i writes lane l's 16B to lds4[i*64+l].
    //    No VGPR round-trip, no ds_write instructions.
#pragma unroll
    for (int i = 0; i < F4PB; ++i) {
        __builtin_amdgcn_global_load_lds(
            (const __attribute__((address_space(1))) uint32_t*)(gf4 + base4 + (i << 6) + tid),
            (__attribute__((address_space(3))) uint32_t*)(&lds4[i << 6]),
            16, 0, 0);
    }

    // 2) R prefetch overlapping the DMA: lane tid -> row (act[b]*64 + tid).
    //    act[b] is wg-uniform -> scalar load; rows are 144 B, 16B-aligned.
    const int a = act[b];                    // s_load
    const f32x4* R4 = (const f32x4*)(Rtab + (size_t)((a << 6) + tid) * MM);
    float R[MM];
#pragma unroll
    for (int q = 0; q < F4PB; ++q) {
        f32x4 rv = R4[q];
        R[4 * q + 0] = rv.x; R[4 * q + 1] = rv.y;
        R[4 * q + 2] = rv.z; R[4 * q + 3] = rv.w;
    }

    __syncthreads();                         // vmcnt(0): DMA + R complete; single-wave wg -> cheap

    // 3) O = R @ G, consuming G one float4 at a time from this thread's own
    //    row (9x ds_read_b128, even bank spread). G element idx=4q+e is
    //    G[j][l] with j=idx/6, l=idx%6 (compile-time): O[:,l] += R[:,j]*g.
    const f32x4* grow4 = (const f32x4*)(&lds4[tid * F4PB]);
    float O[MM];
#pragma unroll
    for (int q = 0; q < F4PB; ++q) {
        f32x4 g = grow4[q];
#pragma unroll
        for (int e = 0; e < 4; ++e) {
            const int idx = 4 * q + e;
            const int j = idx / MDIM;
            const int l = idx - j * MDIM;
            const float gv = g[e];
#pragma unroll
            for (int i = 0; i < MDIM; ++i) {
                if (idx < MDIM)              // j==0: first touch of O[:,l]
                    O[i * MDIM + l] = R[i * MDIM + 0] * gv;
                else
                    O[i * MDIM + l] = fmaf(R[i * MDIM + j], gv, O[i * MDIM + l]);
            }
        }
    }

    // 4) write O back to own row (9x ds_write_b128, even bank spread).
    //    Phases 3/4 touch only this thread's own slice -> no barrier between.
    f32x4* orow = (f32x4*)(&lds4[tid * F4PB]);
#pragma unroll
    for (int q = 0; q < F4PB; ++q) {
        f32x4 v;
        v.x = O[4 * q + 0]; v.y = O[4 * q + 1];
        v.z = O[4 * q + 2]; v.w = O[4 * q + 3];
        orow[q] = v;
    }
    __syncthreads();                         // O visible wave-wide for gather

    // 5) coalesced nontemporal gather-store (contiguous b128 LDS reads)
#pragma unroll
    for (int i = 0; i < F4PB; ++i) {
        int p4 = (i << 6) + tid;
        __builtin_nontemporal_store(lds4[p4], &out4[base4 + p4]);
    }
}

extern "C" void kernel_launch(void* const* d_in, const int* in_sizes, int n_in,
                              void* d_out, int out_size, void* d_ws, size_t ws_size,
                              hipStream_t stream) {
    const float* gf    = (const float*)d_in[0];  // group_feats f32 [B, K*36]
    const int*   act   = (const int*)d_in[1];    // [B] int32
    const float* ap    = (const float*)d_in[2];  // act_params f32 [16,64]
    const float* basis = (const float*)d_in[3];  // lie_alg_basis f32 [64,36]

    float* Rtab = (float*)d_ws;   // 16*64*36*4 = 147456 B of ws

    expm_table_kernel<<<16, 64, 0, stream>>>(ap, basis, Rtab);

    apply_kernel<<<BATCH, WGT, 0, stream>>>((const f32x4*)gf, act, Rtab,
                                            (f32x4*)d_out);
}